// Round 1
// baseline (5197.244 us; speedup 1.0000x reference)
//
#include <hip/hip_runtime.h>

#define DD 64

// out[n][c] (+)= sum_d T[n][d] * W[d][c]  (+ bias[c] if init)
// Block = 256 threads = 4 waves; each 64-lane wave owns one row n.
__global__ __launch_bounds__(256) void gemm_acc_kernel(
    const float* __restrict__ T, const float* __restrict__ W,
    const float* __restrict__ bias, float* __restrict__ out,
    int n_nodes, int init)
{
    __shared__ float Ws[DD * DD];
    for (int i = threadIdx.x; i < DD * DD; i += 256) Ws[i] = W[i];
    __syncthreads();

    int n = blockIdx.x * 4 + (threadIdx.x >> 6);
    int c = threadIdx.x & 63;
    if (n >= n_nodes) return;

    float tr = T[(size_t)n * DD + c];       // lane c holds T[n][c]
    float acc = init ? bias[c] : out[(size_t)n * DD + c];
#pragma unroll
    for (int d = 0; d < DD; ++d)
        acc = fmaf(__shfl(tr, d), Ws[d * DD + c], acc);
    out[(size_t)n * DD + c] = acc;
}

// For each edge e: out[dst_e][*] += scale * w_e * h[src_e][*]
// 16 threads per edge, each handles 4 dims (float4 gather, 4 scalar atomics).
__global__ __launch_bounds__(256) void scatter_kernel(
    const float* __restrict__ h, const int* __restrict__ ei,
    const float* __restrict__ ew, float* __restrict__ out,
    int n_edges, float scale)
{
    int t = blockIdx.x * 256 + threadIdx.x;
    int e = t >> 4;
    if (e >= n_edges) return;
    int q = (t & 15) << 2;

    int src = ei[e];
    int dst = ei[n_edges + e];
    float w = scale * ew[e];

    const float4 v = *reinterpret_cast<const float4*>(&h[(size_t)src * DD + q]);
    float* o = &out[(size_t)dst * DD + q];
    atomicAdd(o + 0, w * v.x);
    atomicAdd(o + 1, w * v.y);
    atomicAdd(o + 2, w * v.z);
    atomicAdd(o + 3, w * v.w);
}

// dst[i] = -src[i]  (seed for T_k = 2*prop(T_{k-1}) - T_{k-2})
__global__ __launch_bounds__(256) void neg_copy_kernel(
    const float* __restrict__ src, float* __restrict__ dst, int n4)
{
    int i = blockIdx.x * 256 + threadIdx.x;
    if (i < n4) {
        float4 v = reinterpret_cast<const float4*>(src)[i];
        v.x = -v.x; v.y = -v.y; v.z = -v.z; v.w = -v.w;
        reinterpret_cast<float4*>(dst)[i] = v;
    }
}

extern "C" void kernel_launch(void* const* d_in, const int* in_sizes, int n_in,
                              void* d_out, int out_size, void* d_ws, size_t ws_size,
                              hipStream_t stream) {
    const float* x    = (const float*)d_in[0];
    const int*   ei   = (const int*)  d_in[1];
    const float* ew   = (const float*)d_in[2];
    const float* W    = (const float*)d_in[3];
    const float* bias = (const float*)d_in[4];
    float* out = (float*)d_out;

    int n_nodes = in_sizes[0] / DD;
    int n_edges = in_sizes[2];
    int K       = in_sizes[3] / (DD * DD);

    size_t nb = (size_t)n_nodes * DD * sizeof(float);
    float* bufs[3] = { (float*)d_ws,
                       (float*)((char*)d_ws + nb),
                       (float*)((char*)d_ws + 2 * nb) };

    int gemm_blocks = (n_nodes + 3) / 4;
    int scat_blocks = (n_edges * 16 + 255) / 256;
    int n4          = (n_nodes * DD) / 4;
    int neg_blocks  = (n4 + 255) / 256;

    // out = x @ W0 + bias          (T_0 = x)
    gemm_acc_kernel<<<gemm_blocks, 256, 0, stream>>>(x, W, bias, out, n_nodes, 1);

    if (K > 1) {
        // T_1 = prop(x)
        hipMemsetAsync(bufs[0], 0, nb, stream);
        scatter_kernel<<<scat_blocks, 256, 0, stream>>>(x, ei, ew, bufs[0], n_edges, 1.0f);
        gemm_acc_kernel<<<gemm_blocks, 256, 0, stream>>>(bufs[0], W + DD * DD, bias, out, n_nodes, 0);
    }

    const float* prev = x;        // T_{k-2}
    const float* cur  = bufs[0];  // T_{k-1}
    int next_idx = 1;
    for (int k = 2; k < K; ++k) {
        float* next = bufs[next_idx];
        // next = -T_{k-2}; next += 2 * prop(T_{k-1})
        neg_copy_kernel<<<neg_blocks, 256, 0, stream>>>(prev, next, n4);
        scatter_kernel<<<scat_blocks, 256, 0, stream>>>(cur, ei, ew, next, n_edges, 2.0f);
        gemm_acc_kernel<<<gemm_blocks, 256, 0, stream>>>(next, W + (size_t)k * DD * DD, bias, out, n_nodes, 0);
        prev = cur; cur = next;
        next_idx = (next_idx + 1) % 3;
    }
}

// Round 3
// 766.920 us; speedup vs baseline: 6.7768x; 6.7768x over previous
//
#include <hip/hip_runtime.h>

#define DD 64

// ---------------- CSR build (by destination) ----------------

__global__ __launch_bounds__(256) void hist_kernel(
    const int* __restrict__ ei, int* __restrict__ cnt, int E)
{
    int e = blockIdx.x * 256 + threadIdx.x;
    if (e < E) atomicAdd(&cnt[ei[E + e]], 1);
}

// per-256-tile sums
__global__ __launch_bounds__(256) void scanA_kernel(
    const int* __restrict__ cnt, int* __restrict__ bsum, int N)
{
    __shared__ int s[256];
    int idx = blockIdx.x * 256 + threadIdx.x;
    s[threadIdx.x] = (idx < N) ? cnt[idx] : 0;
    __syncthreads();
    for (int off = 128; off > 0; off >>= 1) {
        if (threadIdx.x < off) s[threadIdx.x] += s[threadIdx.x + off];
        __syncthreads();
    }
    if (threadIdx.x == 0) bsum[blockIdx.x] = s[0];
}

// exclusive scan of bsum[nb] in place; single block, any nb
__global__ __launch_bounds__(256) void scanB_kernel(int* __restrict__ bsum, int nb)
{
    __shared__ int s[256];
    int carry = 0;
    for (int base = 0; base < nb; base += 256) {
        int i = base + threadIdx.x;
        int v = (i < nb) ? bsum[i] : 0;
        s[threadIdx.x] = v;
        __syncthreads();
        for (int off = 1; off < 256; off <<= 1) {
            int t = (threadIdx.x >= off) ? s[threadIdx.x - off] : 0;
            __syncthreads();
            s[threadIdx.x] += t;
            __syncthreads();
        }
        if (i < nb) bsum[i] = carry + s[threadIdx.x] - v;   // exclusive
        int tot = s[255];
        __syncthreads();
        carry += tot;
    }
}

__global__ __launch_bounds__(256) void scanC_kernel(
    const int* __restrict__ cnt, const int* __restrict__ bsum,
    int* __restrict__ row_ptr, int N, int E)
{
    __shared__ int s[256];
    int idx = blockIdx.x * 256 + threadIdx.x;
    int v = (idx < N) ? cnt[idx] : 0;
    s[threadIdx.x] = v;
    __syncthreads();
    for (int off = 1; off < 256; off <<= 1) {
        int t = (threadIdx.x >= off) ? s[threadIdx.x - off] : 0;
        __syncthreads();
        s[threadIdx.x] += t;
        __syncthreads();
    }
    if (idx < N) row_ptr[idx] = s[threadIdx.x] - v + bsum[blockIdx.x];
    if (idx == N) row_ptr[N] = E;
}

// scatter edges into CSR slots: edges[pos] = (src_bits, w)
__global__ __launch_bounds__(256) void fill_kernel(
    const int* __restrict__ ei, const float* __restrict__ ew,
    int* __restrict__ cursor, float2* __restrict__ edges, int E)
{
    int e = blockIdx.x * 256 + threadIdx.x;
    if (e >= E) return;
    int dst = ei[E + e];
    int pos = atomicAdd(&cursor[dst], 1);
    edges[pos] = make_float2(__int_as_float(ei[e]), ew[e]);
}

// ---------------- compute kernels ----------------

// out[n][c] = bias[c] + sum_d T[n][d]*W[d][c]   (T_0 term)
__global__ __launch_bounds__(256) void gemm_init_kernel(
    const float* __restrict__ T, const float* __restrict__ W,
    const float* __restrict__ bias, float* __restrict__ out, int N)
{
    __shared__ float Ws[DD * DD];
    for (int i = threadIdx.x; i < DD * DD; i += 256) Ws[i] = W[i];
    __syncthreads();
    int n = blockIdx.x * 4 + (threadIdx.x >> 6);
    int c = threadIdx.x & 63;
    if (n >= N) return;
    float tr = T[(size_t)n * DD + c];
    float acc = bias[c];
#pragma unroll
    for (int d = 0; d < DD; ++d)
        acc = fmaf(__shfl(tr, d), Ws[d * DD + c], acc);
    out[(size_t)n * DD + c] = acc;
}

// Fused: t = sum_{e in CSR[n]} w_e * h[src_e][c];
//        if (prev) t = 2*t - prev[n][c];
//        Tnext[n][c] = t;  out[n][c] += sum_d shfl(t,d)*Wk[d][c]
// One 64-lane wave per node, 4 waves/block.
// ALIASING CONTRACT: Tnext may alias prev (each thread reads prev[n,c]
// before writing Tnext[n,c] at the same address; no other thread touches
// that address). Tnext must NOT alias h (gather source) or x.
__global__ __launch_bounds__(256) void prop_fused_kernel(
    const float* __restrict__ h, const float* __restrict__ prev,
    const float2* __restrict__ edges, const int* __restrict__ row_ptr,
    const float* __restrict__ Wk, float* __restrict__ out,
    float* __restrict__ Tnext, int N)
{
    __shared__ float Ws[DD * DD];
    for (int i = threadIdx.x; i < DD * DD; i += 256) Ws[i] = Wk[i];
    __syncthreads();

    int n = blockIdx.x * 4 + (threadIdx.x >> 6);
    int c = threadIdx.x & 63;
    if (n >= N) return;

    int beg = row_ptr[n], end = row_ptr[n + 1];
    float acc = 0.f;
    int e = beg;
    // unroll-by-2 to keep two gathers in flight
    for (; e + 1 < end; e += 2) {
        float2 s0 = edges[e];
        float2 s1 = edges[e + 1];
        float v0 = h[(size_t)__float_as_int(s0.x) * DD + c];
        float v1 = h[(size_t)__float_as_int(s1.x) * DD + c];
        acc = fmaf(s0.y, v0, acc);
        acc = fmaf(s1.y, v1, acc);
    }
    if (e < end) {
        float2 s0 = edges[e];
        acc = fmaf(s0.y, h[(size_t)__float_as_int(s0.x) * DD + c], acc);
    }

    if (prev) acc = 2.f * acc - prev[(size_t)n * DD + c];
    Tnext[(size_t)n * DD + c] = acc;

    float o = out[(size_t)n * DD + c];
#pragma unroll
    for (int d = 0; d < DD; ++d)
        o = fmaf(__shfl(acc, d), Ws[d * DD + c], o);
    out[(size_t)n * DD + c] = o;
}

// ---------------- launch ----------------

static inline size_t rup(size_t x) { return (x + 255) & ~(size_t)255; }

extern "C" void kernel_launch(void* const* d_in, const int* in_sizes, int n_in,
                              void* d_out, int out_size, void* d_ws, size_t ws_size,
                              hipStream_t stream) {
    const float* x    = (const float*)d_in[0];
    const int*   ei   = (const int*)  d_in[1];
    const float* ew   = (const float*)d_in[2];
    const float* W    = (const float*)d_in[3];
    const float* bias = (const float*)d_in[4];
    float* out = (float*)d_out;

    int N = in_sizes[0] / DD;
    int E = in_sizes[2];
    int K = in_sizes[3] / (DD * DD);

    size_t nb = (size_t)N * DD * sizeof(float);
    int nb_scan = (N + 1 + 255) / 256;

    char* w = (char*)d_ws;
    float*  bufA    = (float*)w;            w += rup(nb);
    float*  bufB    = (float*)w;            w += rup(nb);
    float2* edges   = (float2*)w;           w += rup((size_t)E * sizeof(float2));
    int*    cnt     = (int*)w;              w += rup((size_t)N * sizeof(int));
    int*    row_ptr = (int*)w;              w += rup((size_t)(N + 1) * sizeof(int));
    int*    bsum    = (int*)w;              w += rup((size_t)nb_scan * sizeof(int));

    int eb = (E + 255) / 256;
    int gb = (N + 3) / 4;

    // ---- CSR build ----
    hipMemsetAsync(cnt, 0, (size_t)N * sizeof(int), stream);
    hist_kernel<<<eb, 256, 0, stream>>>(ei, cnt, E);
    scanA_kernel<<<nb_scan, 256, 0, stream>>>(cnt, bsum, N);
    scanB_kernel<<<1, 256, 0, stream>>>(bsum, nb_scan);
    scanC_kernel<<<nb_scan, 256, 0, stream>>>(cnt, bsum, row_ptr, N, E);
    hipMemcpyAsync(cnt, row_ptr, (size_t)N * sizeof(int),
                   hipMemcpyDeviceToDevice, stream);           // cnt -> cursor
    fill_kernel<<<eb, 256, 0, stream>>>(ei, ew, cnt, edges, E);

    // ---- T_0 term ----
    gemm_init_kernel<<<gb, 256, 0, stream>>>(x, W, bias, out, N);

    if (K > 1) {
        // T_1 = prop(x); out += T_1 @ W_1
        prop_fused_kernel<<<gb, 256, 0, stream>>>(
            x, nullptr, edges, row_ptr, W + DD * DD, out, bufA, N);
    }

    // T_k = 2*prop(T_{k-1}) - T_{k-2}; out += T_k @ W_k
    // Rotation (2 buffers):
    //   k=2: prop(bufA, x    -> bufB)
    //   k=3: prop(bufB, bufA -> bufA)   (Tnext aliases prev: safe)
    //   k=4: prop(bufA, bufB -> bufB)   ... alternating
    const float* prev = x;
    float*       cur  = bufA;
    float*       nxt  = bufB;
    for (int k = 2; k < K; ++k) {
        prop_fused_kernel<<<gb, 256, 0, stream>>>(
            cur, prev, edges, row_ptr, W + (size_t)k * DD * DD, out, nxt, N);
        float* old_cur = cur;
        cur  = nxt;          // T_k becomes current
        prev = old_cur;      // T_{k-1} becomes previous
        nxt  = old_cur;      // write T_{k+1} over dead T_{k-1} (alias prev: safe)
    }
}

// Round 4
// 663.142 us; speedup vs baseline: 7.8373x; 1.1565x over previous
//
#include <hip/hip_runtime.h>

#define DD 64

// ---------------- CSR build (by destination) ----------------

__global__ __launch_bounds__(256) void hist_kernel(
    const int* __restrict__ ei, int* __restrict__ cnt, int E)
{
    int e = blockIdx.x * 256 + threadIdx.x;
    if (e < E) atomicAdd(&cnt[ei[E + e]], 1);
}

// per-256-tile sums
__global__ __launch_bounds__(256) void scanA_kernel(
    const int* __restrict__ cnt, int* __restrict__ bsum, int N)
{
    __shared__ int s[256];
    int idx = blockIdx.x * 256 + threadIdx.x;
    s[threadIdx.x] = (idx < N) ? cnt[idx] : 0;
    __syncthreads();
    for (int off = 128; off > 0; off >>= 1) {
        if (threadIdx.x < off) s[threadIdx.x] += s[threadIdx.x + off];
        __syncthreads();
    }
    if (threadIdx.x == 0) bsum[blockIdx.x] = s[0];
}

// exclusive scan of bsum[nb] in place; single block, any nb
__global__ __launch_bounds__(256) void scanB_kernel(int* __restrict__ bsum, int nb)
{
    __shared__ int s[256];
    int carry = 0;
    for (int base = 0; base < nb; base += 256) {
        int i = base + threadIdx.x;
        int v = (i < nb) ? bsum[i] : 0;
        s[threadIdx.x] = v;
        __syncthreads();
        for (int off = 1; off < 256; off <<= 1) {
            int t = (threadIdx.x >= off) ? s[threadIdx.x - off] : 0;
            __syncthreads();
            s[threadIdx.x] += t;
            __syncthreads();
        }
        if (i < nb) bsum[i] = carry + s[threadIdx.x] - v;   // exclusive
        int tot = s[255];
        __syncthreads();
        carry += tot;
    }
}

__global__ __launch_bounds__(256) void scanC_kernel(
    const int* __restrict__ cnt, const int* __restrict__ bsum,
    int* __restrict__ row_ptr, int N, int E)
{
    __shared__ int s[256];
    int idx = blockIdx.x * 256 + threadIdx.x;
    int v = (idx < N) ? cnt[idx] : 0;
    s[threadIdx.x] = v;
    __syncthreads();
    for (int off = 1; off < 256; off <<= 1) {
        int t = (threadIdx.x >= off) ? s[threadIdx.x - off] : 0;
        __syncthreads();
        s[threadIdx.x] += t;
        __syncthreads();
    }
    if (idx < N) row_ptr[idx] = s[threadIdx.x] - v + bsum[blockIdx.x];
    if (idx == N) row_ptr[N] = E;
}

// scatter edges into CSR slots: edges[pos] = (src_bits, w)
__global__ __launch_bounds__(256) void fill_kernel(
    const int* __restrict__ ei, const float* __restrict__ ew,
    int* __restrict__ cursor, float2* __restrict__ edges, int E)
{
    int e = blockIdx.x * 256 + threadIdx.x;
    if (e >= E) return;
    int dst = ei[E + e];
    int pos = atomicAdd(&cursor[dst], 1);
    edges[pos] = make_float2(__int_as_float(ei[e]), ew[e]);
}

// ---------------- compute kernels ----------------

// out[n][c] = bias[c] + sum_d T[n][d]*W[d][c]   (T_0 term)
__global__ __launch_bounds__(256) void gemm_init_kernel(
    const float* __restrict__ T, const float* __restrict__ W,
    const float* __restrict__ bias, float* __restrict__ out, int N)
{
    __shared__ float Ws[DD * DD];
    for (int i = threadIdx.x; i < DD * DD; i += 256) Ws[i] = W[i];
    __syncthreads();
    int n = blockIdx.x * 4 + (threadIdx.x >> 6);
    int c = threadIdx.x & 63;
    if (n >= N) return;
    float tr = T[(size_t)n * DD + c];
    float acc = bias[c];
#pragma unroll
    for (int d = 0; d < DD; ++d)
        acc = fmaf(__shfl(tr, d), Ws[d * DD + c], acc);
    out[(size_t)n * DD + c] = acc;
}

// Fused propagate + recurrence + GEMM accumulate. One 64-lane wave per node,
// 4 waves/block. Within the wave: 4 groups x 16 lanes; each group gathers one
// edge's 256B row via float4/lane, so 8 row-gathers are in flight per wave
// (2-batch unroll x 4 groups). Cross-group xor-shuffle reduce, then
// t = 2*t - prev, Tnext = t, out += t @ Wk (LDS W, shfl row-broadcast).
// ALIASING CONTRACT: Tnext may alias prev; must NOT alias h.
__global__ __launch_bounds__(256) void prop_fused_kernel(
    const float* __restrict__ h, const float* __restrict__ prev,
    const float2* __restrict__ edges, const int* __restrict__ row_ptr,
    const float* __restrict__ Wk, float* __restrict__ out,
    float* __restrict__ Tnext, int N)
{
    __shared__ float Ws[DD * DD];
    for (int i = threadIdx.x; i < DD * DD; i += 256) Ws[i] = Wk[i];
    __syncthreads();

    int lane = threadIdx.x & 63;
    int n = blockIdx.x * 4 + (threadIdx.x >> 6);
    if (n >= N) return;

    int g = lane >> 4;        // edge group 0..3
    int q = (lane & 15) << 2; // channel base for this lane's float4 slice

    int beg = row_ptr[n], end = row_ptr[n + 1];

    float4 acc = make_float4(0.f, 0.f, 0.f, 0.f);
    const float2 zed = make_float2(__int_as_float(0), 0.f);
    for (int base = beg; base < end; base += 8) {
        int ea = base + g;
        int eb = base + 4 + g;
        float2 EA = (ea < end) ? edges[ea] : zed;
        float2 EB = (eb < end) ? edges[eb] : zed;
        float4 va = *reinterpret_cast<const float4*>(
            &h[(size_t)__float_as_int(EA.x) * DD + q]);
        float4 vb = *reinterpret_cast<const float4*>(
            &h[(size_t)__float_as_int(EB.x) * DD + q]);
        acc.x = fmaf(EA.y, va.x, acc.x);
        acc.y = fmaf(EA.y, va.y, acc.y);
        acc.z = fmaf(EA.y, va.z, acc.z);
        acc.w = fmaf(EA.y, va.w, acc.w);
        acc.x = fmaf(EB.y, vb.x, acc.x);
        acc.y = fmaf(EB.y, vb.y, acc.y);
        acc.z = fmaf(EB.y, vb.z, acc.z);
        acc.w = fmaf(EB.y, vb.w, acc.w);
    }

    // reduce partials across the 4 groups (lanes ^16, ^32)
#pragma unroll
    for (int m = 16; m <= 32; m <<= 1) {
        acc.x += __shfl_xor(acc.x, m);
        acc.y += __shfl_xor(acc.y, m);
        acc.z += __shfl_xor(acc.z, m);
        acc.w += __shfl_xor(acc.w, m);
    }

    if (prev) {
        const float4 p = *reinterpret_cast<const float4*>(&prev[(size_t)n * DD + q]);
        acc.x = 2.f * acc.x - p.x;
        acc.y = 2.f * acc.y - p.y;
        acc.z = 2.f * acc.z - p.z;
        acc.w = 2.f * acc.w - p.w;
    }
    if (g == 0)
        *reinterpret_cast<float4*>(&Tnext[(size_t)n * DD + q]) = acc;

    // out[n][lane] += sum_d T[n][d] * Wk[d][lane]
    float o = out[(size_t)n * DD + lane];
#pragma unroll
    for (int sl = 0; sl < 16; ++sl) {
        float tx = __shfl(acc.x, sl);
        float ty = __shfl(acc.y, sl);
        float tz = __shfl(acc.z, sl);
        float tw = __shfl(acc.w, sl);
        o = fmaf(tx, Ws[(4 * sl + 0) * DD + lane], o);
        o = fmaf(ty, Ws[(4 * sl + 1) * DD + lane], o);
        o = fmaf(tz, Ws[(4 * sl + 2) * DD + lane], o);
        o = fmaf(tw, Ws[(4 * sl + 3) * DD + lane], o);
    }
    out[(size_t)n * DD + lane] = o;
}

// ---------------- launch ----------------

static inline size_t rup(size_t x) { return (x + 255) & ~(size_t)255; }

extern "C" void kernel_launch(void* const* d_in, const int* in_sizes, int n_in,
                              void* d_out, int out_size, void* d_ws, size_t ws_size,
                              hipStream_t stream) {
    const float* x    = (const float*)d_in[0];
    const int*   ei   = (const int*)  d_in[1];
    const float* ew   = (const float*)d_in[2];
    const float* W    = (const float*)d_in[3];
    const float* bias = (const float*)d_in[4];
    float* out = (float*)d_out;

    int N = in_sizes[0] / DD;
    int E = in_sizes[2];
    int K = in_sizes[3] / (DD * DD);

    size_t nb = (size_t)N * DD * sizeof(float);
    int nb_scan = (N + 1 + 255) / 256;

    char* w = (char*)d_ws;
    float*  bufA    = (float*)w;            w += rup(nb);
    float*  bufB    = (float*)w;            w += rup(nb);
    float2* edges   = (float2*)w;           w += rup((size_t)E * sizeof(float2));
    int*    cnt     = (int*)w;              w += rup((size_t)N * sizeof(int));
    int*    row_ptr = (int*)w;              w += rup((size_t)(N + 1) * sizeof(int));
    int*    bsum    = (int*)w;              w += rup((size_t)nb_scan * sizeof(int));

    int eb = (E + 255) / 256;
    int gb = (N + 3) / 4;

    // ---- CSR build ----
    hipMemsetAsync(cnt, 0, (size_t)N * sizeof(int), stream);
    hist_kernel<<<eb, 256, 0, stream>>>(ei, cnt, E);
    scanA_kernel<<<nb_scan, 256, 0, stream>>>(cnt, bsum, N);
    scanB_kernel<<<1, 256, 0, stream>>>(bsum, nb_scan);
    scanC_kernel<<<nb_scan, 256, 0, stream>>>(cnt, bsum, row_ptr, N, E);
    hipMemcpyAsync(cnt, row_ptr, (size_t)N * sizeof(int),
                   hipMemcpyDeviceToDevice, stream);           // cnt -> cursor
    fill_kernel<<<eb, 256, 0, stream>>>(ei, ew, cnt, edges, E);

    // ---- T_0 term ----
    gemm_init_kernel<<<gb, 256, 0, stream>>>(x, W, bias, out, N);

    if (K > 1) {
        // T_1 = prop(x); out += T_1 @ W_1
        prop_fused_kernel<<<gb, 256, 0, stream>>>(
            x, nullptr, edges, row_ptr, W + DD * DD, out, bufA, N);
    }

    // T_k = 2*prop(T_{k-1}) - T_{k-2}; out += T_k @ W_k
    // Rotation (2 buffers):
    //   k=2: prop(bufA, x    -> bufB)
    //   k=3: prop(bufB, bufA -> bufA)   (Tnext aliases prev: safe)
    //   k=4: prop(bufA, bufB -> bufB)   ... alternating
    const float* prev = x;
    float*       cur  = bufA;
    float*       nxt  = bufB;
    for (int k = 2; k < K; ++k) {
        prop_fused_kernel<<<gb, 256, 0, stream>>>(
            cur, prev, edges, row_ptr, W + (size_t)k * DD * DD, out, nxt, N);
        float* old_cur = cur;
        cur  = nxt;          // T_k becomes current
        prev = old_cur;      // T_{k-1} becomes previous
        nxt  = old_cur;      // write T_{k+1} over dead T_{k-1} (alias prev: safe)
    }
}

// Round 5
// 662.553 us; speedup vs baseline: 7.8443x; 1.0009x over previous
//
#include <hip/hip_runtime.h>

#define DD 64

// ---------------- CSR build (by destination) ----------------

__global__ __launch_bounds__(256) void hist_kernel(
    const int* __restrict__ ei, int* __restrict__ cnt, int E)
{
    int e = blockIdx.x * 256 + threadIdx.x;
    if (e < E) atomicAdd(&cnt[ei[E + e]], 1);
}

// per-256-tile sums
__global__ __launch_bounds__(256) void scanA_kernel(
    const int* __restrict__ cnt, int* __restrict__ bsum, int N)
{
    __shared__ int s[256];
    int idx = blockIdx.x * 256 + threadIdx.x;
    s[threadIdx.x] = (idx < N) ? cnt[idx] : 0;
    __syncthreads();
    for (int off = 128; off > 0; off >>= 1) {
        if (threadIdx.x < off) s[threadIdx.x] += s[threadIdx.x + off];
        __syncthreads();
    }
    if (threadIdx.x == 0) bsum[blockIdx.x] = s[0];
}

// exclusive scan of bsum[nb] in place; single block, any nb
__global__ __launch_bounds__(256) void scanB_kernel(int* __restrict__ bsum, int nb)
{
    __shared__ int s[256];
    int carry = 0;
    for (int base = 0; base < nb; base += 256) {
        int i = base + threadIdx.x;
        int v = (i < nb) ? bsum[i] : 0;
        s[threadIdx.x] = v;
        __syncthreads();
        for (int off = 1; off < 256; off <<= 1) {
            int t = (threadIdx.x >= off) ? s[threadIdx.x - off] : 0;
            __syncthreads();
            s[threadIdx.x] += t;
            __syncthreads();
        }
        if (i < nb) bsum[i] = carry + s[threadIdx.x] - v;   // exclusive
        int tot = s[255];
        __syncthreads();
        carry += tot;
    }
}

__global__ __launch_bounds__(256) void scanC_kernel(
    const int* __restrict__ cnt, const int* __restrict__ bsum,
    int* __restrict__ row_ptr, int N, int E)
{
    __shared__ int s[256];
    int idx = blockIdx.x * 256 + threadIdx.x;
    int v = (idx < N) ? cnt[idx] : 0;
    s[threadIdx.x] = v;
    __syncthreads();
    for (int off = 1; off < 256; off <<= 1) {
        int t = (threadIdx.x >= off) ? s[threadIdx.x - off] : 0;
        __syncthreads();
        s[threadIdx.x] += t;
        __syncthreads();
    }
    if (idx < N) row_ptr[idx] = s[threadIdx.x] - v + bsum[blockIdx.x];
    if (idx == N) row_ptr[N] = E;
}

// scatter edges into CSR slots: edges[pos] = (src_bits, w)
__global__ __launch_bounds__(256) void fill_kernel(
    const int* __restrict__ ei, const float* __restrict__ ew,
    int* __restrict__ cursor, float2* __restrict__ edges, int E)
{
    int e = blockIdx.x * 256 + threadIdx.x;
    if (e >= E) return;
    int dst = ei[E + e];
    int pos = atomicAdd(&cursor[dst], 1);
    edges[pos] = make_float2(__int_as_float(ei[e]), ew[e]);
}

// ---------------- compute kernels ----------------

// out[n][c] = bias[c] + sum_d T[n][d]*W[d][c]   (T_0 term)
__global__ __launch_bounds__(256) void gemm_init_kernel(
    const float* __restrict__ T, const float* __restrict__ W,
    const float* __restrict__ bias, float* __restrict__ out, int N)
{
    __shared__ float Ws[DD * DD];
    for (int i = threadIdx.x; i < DD * DD; i += 256) Ws[i] = W[i];
    __syncthreads();
    int n = blockIdx.x * 4 + (threadIdx.x >> 6);
    int c = threadIdx.x & 63;
    if (n >= N) return;
    float tr = T[(size_t)n * DD + c];
    float acc = bias[c];
#pragma unroll
    for (int d = 0; d < DD; ++d)
        acc = fmaf(__shfl(tr, d), Ws[d * DD + c], acc);
    out[(size_t)n * DD + c] = acc;
}

// Fused propagate + recurrence + GEMM accumulate. One 64-lane wave per node,
// 4 waves/block. Within the wave: 8 groups x 8 lanes; each group gathers one
// edge's 256B row, each lane covering 8 channels via two float4 loads.
// => 16 edges per iteration, 32 wave-wide row-gathers in flight (4/lane).
// Mean row length = 16, so most rows take ONE iteration.
// Cross-group xor-shuffle reduce (masks 8/16/32), then t = 2*t - prev,
// Tnext = t (group 0 writes), out += t @ Wk (LDS W, shfl row-broadcast).
// ALIASING CONTRACT: Tnext may alias prev; must NOT alias h.
__global__ __launch_bounds__(256) void prop_fused_kernel(
    const float* __restrict__ h, const float* __restrict__ prev,
    const float2* __restrict__ edges, const int* __restrict__ row_ptr,
    const float* __restrict__ Wk, float* __restrict__ out,
    float* __restrict__ Tnext, int N)
{
    __shared__ float Ws[DD * DD];
    for (int i = threadIdx.x; i < DD * DD; i += 256) Ws[i] = Wk[i];
    __syncthreads();

    int lane = threadIdx.x & 63;
    int n = blockIdx.x * 4 + (threadIdx.x >> 6);
    if (n >= N) return;

    int g  = lane >> 3;        // edge group 0..7
    int c8 = (lane & 7) << 3;  // channel base: 8 channels per lane

    int beg = row_ptr[n], end = row_ptr[n + 1];

    float4 acc0 = make_float4(0.f, 0.f, 0.f, 0.f);
    float4 acc1 = make_float4(0.f, 0.f, 0.f, 0.f);
    const float2 zed = make_float2(__int_as_float(0), 0.f);

    for (int base = beg; base < end; base += 16) {
        int ea = base + g;
        int eb = base + 8 + g;
        float2 EA = (ea < end) ? edges[ea] : zed;
        float2 EB = (eb < end) ? edges[eb] : zed;
        const float* ra = &h[(size_t)__float_as_int(EA.x) * DD + c8];
        const float* rb = &h[(size_t)__float_as_int(EB.x) * DD + c8];
        float4 va0 = *reinterpret_cast<const float4*>(ra);
        float4 va1 = *reinterpret_cast<const float4*>(ra + 4);
        float4 vb0 = *reinterpret_cast<const float4*>(rb);
        float4 vb1 = *reinterpret_cast<const float4*>(rb + 4);
        acc0.x = fmaf(EA.y, va0.x, acc0.x);
        acc0.y = fmaf(EA.y, va0.y, acc0.y);
        acc0.z = fmaf(EA.y, va0.z, acc0.z);
        acc0.w = fmaf(EA.y, va0.w, acc0.w);
        acc1.x = fmaf(EA.y, va1.x, acc1.x);
        acc1.y = fmaf(EA.y, va1.y, acc1.y);
        acc1.z = fmaf(EA.y, va1.z, acc1.z);
        acc1.w = fmaf(EA.y, va1.w, acc1.w);
        acc0.x = fmaf(EB.y, vb0.x, acc0.x);
        acc0.y = fmaf(EB.y, vb0.y, acc0.y);
        acc0.z = fmaf(EB.y, vb0.z, acc0.z);
        acc0.w = fmaf(EB.y, vb0.w, acc0.w);
        acc1.x = fmaf(EB.y, vb1.x, acc1.x);
        acc1.y = fmaf(EB.y, vb1.y, acc1.y);
        acc1.z = fmaf(EB.y, vb1.z, acc1.z);
        acc1.w = fmaf(EB.y, vb1.w, acc1.w);
    }

    // reduce partials across the 8 groups (lane bits 3,4,5)
#pragma unroll
    for (int m = 8; m <= 32; m <<= 1) {
        acc0.x += __shfl_xor(acc0.x, m);
        acc0.y += __shfl_xor(acc0.y, m);
        acc0.z += __shfl_xor(acc0.z, m);
        acc0.w += __shfl_xor(acc0.w, m);
        acc1.x += __shfl_xor(acc1.x, m);
        acc1.y += __shfl_xor(acc1.y, m);
        acc1.z += __shfl_xor(acc1.z, m);
        acc1.w += __shfl_xor(acc1.w, m);
    }

    if (prev) {
        const float4 p0 = *reinterpret_cast<const float4*>(&prev[(size_t)n * DD + c8]);
        const float4 p1 = *reinterpret_cast<const float4*>(&prev[(size_t)n * DD + c8 + 4]);
        acc0.x = 2.f * acc0.x - p0.x;
        acc0.y = 2.f * acc0.y - p0.y;
        acc0.z = 2.f * acc0.z - p0.z;
        acc0.w = 2.f * acc0.w - p0.w;
        acc1.x = 2.f * acc1.x - p1.x;
        acc1.y = 2.f * acc1.y - p1.y;
        acc1.z = 2.f * acc1.z - p1.z;
        acc1.w = 2.f * acc1.w - p1.w;
    }
    if (g == 0) {
        *reinterpret_cast<float4*>(&Tnext[(size_t)n * DD + c8]) = acc0;
        *reinterpret_cast<float4*>(&Tnext[(size_t)n * DD + c8 + 4]) = acc1;
    }

    // out[n][lane] += sum_d T[n][d] * Wk[d][lane]
    // value for d = sl*8+j lives in lane sl (lanes 0..7 have lane&7 == lane)
    float o = out[(size_t)n * DD + lane];
#pragma unroll
    for (int sl = 0; sl < 8; ++sl) {
        float t0 = __shfl(acc0.x, sl);
        float t1 = __shfl(acc0.y, sl);
        float t2 = __shfl(acc0.z, sl);
        float t3 = __shfl(acc0.w, sl);
        float t4 = __shfl(acc1.x, sl);
        float t5 = __shfl(acc1.y, sl);
        float t6 = __shfl(acc1.z, sl);
        float t7 = __shfl(acc1.w, sl);
        o = fmaf(t0, Ws[(8 * sl + 0) * DD + lane], o);
        o = fmaf(t1, Ws[(8 * sl + 1) * DD + lane], o);
        o = fmaf(t2, Ws[(8 * sl + 2) * DD + lane], o);
        o = fmaf(t3, Ws[(8 * sl + 3) * DD + lane], o);
        o = fmaf(t4, Ws[(8 * sl + 4) * DD + lane], o);
        o = fmaf(t5, Ws[(8 * sl + 5) * DD + lane], o);
        o = fmaf(t6, Ws[(8 * sl + 6) * DD + lane], o);
        o = fmaf(t7, Ws[(8 * sl + 7) * DD + lane], o);
    }
    out[(size_t)n * DD + lane] = o;
}

// ---------------- launch ----------------

static inline size_t rup(size_t x) { return (x + 255) & ~(size_t)255; }

extern "C" void kernel_launch(void* const* d_in, const int* in_sizes, int n_in,
                              void* d_out, int out_size, void* d_ws, size_t ws_size,
                              hipStream_t stream) {
    const float* x    = (const float*)d_in[0];
    const int*   ei   = (const int*)  d_in[1];
    const float* ew   = (const float*)d_in[2];
    const float* W    = (const float*)d_in[3];
    const float* bias = (const float*)d_in[4];
    float* out = (float*)d_out;

    int N = in_sizes[0] / DD;
    int E = in_sizes[2];
    int K = in_sizes[3] / (DD * DD);

    size_t nb = (size_t)N * DD * sizeof(float);
    int nb_scan = (N + 1 + 255) / 256;

    char* w = (char*)d_ws;
    float*  bufA    = (float*)w;            w += rup(nb);
    float*  bufB    = (float*)w;            w += rup(nb);
    float2* edges   = (float2*)w;           w += rup((size_t)E * sizeof(float2));
    int*    cnt     = (int*)w;              w += rup((size_t)N * sizeof(int));
    int*    row_ptr = (int*)w;              w += rup((size_t)(N + 1) * sizeof(int));
    int*    bsum    = (int*)w;              w += rup((size_t)nb_scan * sizeof(int));

    int eb = (E + 255) / 256;
    int gb = (N + 3) / 4;

    // ---- CSR build ----
    hipMemsetAsync(cnt, 0, (size_t)N * sizeof(int), stream);
    hist_kernel<<<eb, 256, 0, stream>>>(ei, cnt, E);
    scanA_kernel<<<nb_scan, 256, 0, stream>>>(cnt, bsum, N);
    scanB_kernel<<<1, 256, 0, stream>>>(bsum, nb_scan);
    scanC_kernel<<<nb_scan, 256, 0, stream>>>(cnt, bsum, row_ptr, N, E);
    hipMemcpyAsync(cnt, row_ptr, (size_t)N * sizeof(int),
                   hipMemcpyDeviceToDevice, stream);           // cnt -> cursor
    fill_kernel<<<eb, 256, 0, stream>>>(ei, ew, cnt, edges, E);

    // ---- T_0 term ----
    gemm_init_kernel<<<gb, 256, 0, stream>>>(x, W, bias, out, N);

    if (K > 1) {
        // T_1 = prop(x); out += T_1 @ W_1
        prop_fused_kernel<<<gb, 256, 0, stream>>>(
            x, nullptr, edges, row_ptr, W + DD * DD, out, bufA, N);
    }

    // T_k = 2*prop(T_{k-1}) - T_{k-2}; out += T_k @ W_k
    // Rotation (2 buffers):
    //   k=2: prop(bufA, x    -> bufB)
    //   k=3: prop(bufB, bufA -> bufA)   (Tnext aliases prev: safe)
    //   k=4: prop(bufA, bufB -> bufB)   ... alternating
    const float* prev = x;
    float*       cur  = bufA;
    float*       nxt  = bufB;
    for (int k = 2; k < K; ++k) {
        prop_fused_kernel<<<gb, 256, 0, stream>>>(
            cur, prev, edges, row_ptr, W + (size_t)k * DD * DD, out, nxt, N);
        float* old_cur = cur;
        cur  = nxt;          // T_k becomes current
        prev = old_cur;      // T_{k-1} becomes previous
        nxt  = old_cur;      // write T_{k+1} over dead T_{k-1} (alias prev: safe)
    }
}